// Round 4
// baseline (25223.036 us; speedup 1.0000x reference)
//
#include <hip/hip_runtime.h>
#include <stdint.h>

typedef unsigned short ushort_t;
typedef unsigned long long u64;
typedef __attribute__((ext_vector_type(8))) short short8;
typedef __attribute__((ext_vector_type(4))) float f32x4;
typedef __attribute__((ext_vector_type(16))) float f32x16;

#define WS_W0T_HI 0u
#define WS_W0T_LO (2u<<20)
#define WS_WST_HI (4u<<20)
#define WS_WST_LO (12u<<20)
#define WS_ST     (20u<<20)
#define WS_BAR    (26u<<20)

#define SLOT_ELEMS 262144   // per state slot (hi plane + lo plane), elements
#define PLANE 131072        // 256*512

// state slots: 0=h, 1=s0, 2=s1, 3=s2, 4=s3, 5=s5

__device__ __forceinline__ ushort_t f2bf(float f) {
  unsigned u = __float_as_uint(f);
  u += 0x7FFFu + ((u >> 16) & 1u);          // RNE to bf16
  return (ushort_t)(u >> 16);
}
__device__ __forceinline__ float bf2f(ushort_t h) {
  return __uint_as_float(((unsigned)h) << 16);
}
__device__ __forceinline__ float sigf(float v) { return 1.f / (1.f + __expf(-v)); }

// 16B state-fragment load via 2x8B relaxed agent atomics (coherent, no fences)
__device__ __forceinline__ short8 ald16(const ushort_t* p) {
  union { u64 q[2]; short8 s; } u;
  u.q[0] = __hip_atomic_load((const u64*)p,     __ATOMIC_RELAXED, __HIP_MEMORY_SCOPE_AGENT);
  u.q[1] = __hip_atomic_load((const u64*)p + 1, __ATOMIC_RELAXED, __HIP_MEMORY_SCOPE_AGENT);
  return u.s;
}

// convert 8 f32 (plain cached loads) -> bf16 hi/lo fragments
__device__ __forceinline__ void xcvt(const float* xp, short8& ah, short8& al) {
  f32x4 v0 = *(const f32x4*)xp;
  f32x4 v1 = *(const f32x4*)(xp + 4);
#pragma unroll
  for (int i = 0; i < 4; ++i) {
    ushort_t h0 = f2bf(v0[i]);
    ah[i] = (short)h0; al[i] = (short)f2bf(v0[i] - bf2f(h0));
    ushort_t h1 = f2bf(v1[i]);
    ah[i + 4] = (short)h1; al[i + 4] = (short)f2bf(v1[i] - bf2f(h1));
  }
}

// paired-column state store via relaxed agent atomics
__device__ __forceinline__ void st_state(ushort_t* slot, int eo, float s) {
  ushort_t hi = f2bf(s);
  ushort_t lo = f2bf(s - bf2f(hi));
  unsigned nh = __shfl_xor((unsigned)hi, 1, 64);
  unsigned nl = __shfl_xor((unsigned)lo, 1, 64);
  if ((threadIdx.x & 1) == 0) {
    unsigned wh = (unsigned)hi | (nh << 16);
    unsigned wl = (unsigned)lo | (nl << 16);
    __hip_atomic_store((unsigned*)(slot + eo), wh, __ATOMIC_RELAXED, __HIP_MEMORY_SCOPE_AGENT);
    __hip_atomic_store((unsigned*)(slot + PLANE + eo), wl, __ATOMIC_RELAXED, __HIP_MEMORY_SCOPE_AGENT);
  }
}

// ---------------- prep: transpose + hi/lo split weights; convert h0 ---------
extern "C" __global__ void prep_kernel(const float* __restrict__ W0,
                                       const float* __restrict__ Ws,
                                       const float* __restrict__ h0,
                                       char* __restrict__ ws) {
  ushort_t* w0h = (ushort_t*)(ws + WS_W0T_HI);
  ushort_t* w0l = (ushort_t*)(ws + WS_W0T_LO);
  ushort_t* wsh = (ushort_t*)(ws + WS_WST_HI);
  ushort_t* wsl = (ushort_t*)(ws + WS_WST_LO);
  ushort_t* st  = (ushort_t*)(ws + WS_ST);
  const long N0 = 1048576, N1 = 4194304, N2 = 131072;
  long total = N0 + N1 + N2;
  for (long idx = (long)blockIdx.x * blockDim.x + threadIdx.x; idx < total;
       idx += (long)gridDim.x * blockDim.x) {
    if (idx < N0) {                       // W0T[j][k] from W0[k][j], K=1024
      int k = (int)(idx >> 10), j = (int)(idx & 1023);
      float v = W0[k * 1024 + j];
      ushort_t hi = f2bf(v);
      w0h[j * 1024 + k] = hi;
      w0l[j * 1024 + k] = f2bf(v - bf2f(hi));
    } else if (idx < N0 + N1) {           // WsT[i][j][k] from Ws[i][k][j], K=512
      long r = idx - N0;
      int i = (int)(r >> 19);
      int r2 = (int)(r & 524287);
      int k = r2 >> 10, j = r2 & 1023;
      float v = Ws[(long)i * 524288 + k * 1024 + j];
      ushort_t hi = f2bf(v);
      wsh[(long)i * 524288 + j * 512 + k] = hi;
      wsl[(long)i * 524288 + j * 512 + k] = f2bf(v - bf2f(hi));
    } else {                              // h0 -> slot 0
      int e = (int)(idx - N0 - N1);
      float v = h0[e];
      ushort_t hi = f2bf(v);
      st[0 * SLOT_ELEMS + e] = hi;
      st[0 * SLOT_ELEMS + PLANE + e] = f2bf(v - bf2f(hi));
    }
  }
}

// -------- split barrier: arrive, (warm L2 during wait), then poll ----------
__device__ __forceinline__ void gbar_begin(unsigned* flags, int g, int pt, unsigned gen) {
  __syncthreads();   // drains vmcnt: state stores are at the coherence point
  if (threadIdx.x == 0)
    __hip_atomic_store(flags + (g * 32 + pt) * 16, gen, __ATOMIC_RELAXED, __HIP_MEMORY_SCOPE_AGENT);
}
__device__ __forceinline__ void gbar_end(unsigned* flags, int g, unsigned gen) {
  if (threadIdx.x < 64) {
    const unsigned* f = flags + (g * 32 + (threadIdx.x & 31)) * 16;
    while (__hip_atomic_load(f, __ATOMIC_RELAXED, __HIP_MEMORY_SCOPE_AGENT) < gen)
      __builtin_amdgcn_s_sleep(2);
  }
  __syncthreads();
  asm volatile("" ::: "memory");
}

// warm next stage's weight slice into L2 while waiting at the barrier.
// Touches this WG's 32 columns (both planes) of one matrix, one 4B load/128B line.
template<int K>
__device__ __forceinline__ void warm_w(const ushort_t* wh, const ushort_t* wl, int pt) {
  const int lpc = K >> 6;                 // 128B lines per column
  const int nl = 32 * lpc;                // per plane
  for (int l = threadIdx.x; l < 2 * nl; l += 512) {
    const ushort_t* base = (l >= nl) ? wl : wh;
    int ll = (l >= nl) ? (l - nl) : l;
    int c = ll / lpc, li = ll - c * lpc;  // c in 0..31
    int j = (c < 16) ? (pt * 16 + c) : (512 + pt * 16 + (c - 16));
    unsigned v = *(const unsigned*)(base + j * K + li * 64);
    asm volatile("" :: "v"(v));
  }
}
// warm next timestep's x block (32 rows x 512 f32 = 512 lines)
__device__ __forceinline__ void warm_x(const float* xblk) {
  unsigned v = *(const unsigned*)(xblk + threadIdx.x * 32);
  asm volatile("" :: "v"(v));
}

__device__ __forceinline__ f32x16 mfma3(short8 ah, short8 al, short8 bh, short8 bl, f32x16 acc) {
  acc = __builtin_amdgcn_mfma_f32_32x32x16_bf16(ah, bh, acc, 0, 0, 0);
  acc = __builtin_amdgcn_mfma_f32_32x32x16_bf16(ah, bl, acc, 0, 0, 0);
  acc = __builtin_amdgcn_mfma_f32_32x32x16_bf16(al, bh, acc, 0, 0, 0);
  return acc;
}

// shared-A matmul: NP B-matrices against one A; XH = stage A ([x_f32 | h_slot])
template<int NP, int NBLK, bool XH>
__device__ __forceinline__ void mm_sharedA(const float* xrow, const ushort_t* aslot,
                                           const ushort_t* const (&bh)[NP],
                                           const ushort_t* const (&bl)[NP],
                                           int aoff, int boff, int kw,
                                           f32x16 (&acc)[NP]) {
#pragma unroll
  for (int j = 0; j < NBLK; ++j) {
    int kq = j * 128 + kw;
    short8 a_h, a_l;
    if (XH && j < 4) {
      xcvt(xrow + kq, a_h, a_l);
    } else {
      int kk = XH ? (kq - 512) : kq;
      a_h = ald16(aslot + aoff + kk);
      a_l = ald16(aslot + PLANE + aoff + kk);
    }
#pragma unroll
    for (int p = 0; p < NP; ++p) {
      short8 b_h = *(const short8*)(bh[p] + boff + kq);
      short8 b_l = *(const short8*)(bl[p] + boff + kq);
      acc[p] = mfma3(a_h, a_l, b_h, b_l, acc[p]);
    }
  }
}

// independent-A matmul: pair p uses A[p] and B[p] (stage D)
template<int NP, int NBLK>
__device__ __forceinline__ void mm_pairA(const ushort_t* const (&as)[NP],
                                         const ushort_t* const (&bh)[NP],
                                         const ushort_t* const (&bl)[NP],
                                         int aoff, int boff, int kw,
                                         f32x16 (&acc)[NP]) {
#pragma unroll
  for (int j = 0; j < NBLK; ++j) {
    int kq = j * 128 + kw;
#pragma unroll
    for (int p = 0; p < NP; ++p) {
      short8 a_h = ald16(as[p] + aoff + kq);
      short8 a_l = ald16(as[p] + PLANE + aoff + kq);
      short8 b_h = *(const short8*)(bh[p] + boff + kq);
      short8 b_l = *(const short8*)(bl[p] + boff + kq);
      acc[p] = mfma3(a_h, a_l, b_h, b_l, acc[p]);
    }
  }
}

template<int NP>
__device__ __forceinline__ void store_partials(float* pp, const f32x16 (&acc)[NP],
                                               int w, int lane) {
  int col = lane & 31, hi = lane >> 5;
#pragma unroll
  for (int p = 0; p < NP; ++p) {
#pragma unroll
    for (int r = 0; r < 16; ++r) {
      int row = (r & 3) + 8 * (r >> 2) + 4 * hi;   // verified 32x32 C/D layout
      pp[(w * NP + p) * 1056 + row * 33 + col] = acc[p][r];
    }
  }
}

template<int NP>
__device__ __forceinline__ void red2(const float* pp, int p, int row, int cp,
                                     float& c, float& h) {
  float cs = 0.f, hs = 0.f;
#pragma unroll
  for (int w = 0; w < 8; ++w) {
    cs += pp[(w * NP + p) * 1056 + row * 33 + cp];
    hs += pp[(w * NP + p) * 1056 + row * 33 + cp + 16];
  }
  c = cs; h = hs;
}

// ---------------- main persistent cooperative kernel -----------------------
extern "C" __global__ void __launch_bounds__(512, 1)
rnn_main(const float* __restrict__ x, float* __restrict__ out, char* __restrict__ ws) {
  __shared__ float pp[8 * 3 * 1056];      // 8-wave partials, up to 3 targets
  __shared__ float lst[6][32][16];        // WG-local f32 state tiles: h,s0,s1,s2,s3,s5
  ushort_t* stg = (ushort_t*)(ws + WS_ST);
  unsigned* flags = (unsigned*)(ws + WS_BAR);
  const ushort_t* w0h = (const ushort_t*)(ws + WS_W0T_HI);
  const ushort_t* w0l = (const ushort_t*)(ws + WS_W0T_LO);
  const ushort_t* wsh = (const ushort_t*)(ws + WS_WST_HI);
  const ushort_t* wsl = (const ushort_t*)(ws + WS_WST_LO);

  const int tid = threadIdx.x;
  const int wg = blockIdx.x;
  // XCD-local row groups: dispatch is round-robin (XCD = wg % 8), so rt = wg&7
  // pins each row-group's 32 WGs (and its state exchange + barrier) to ONE XCD.
  const int rt = wg & 7, pt = wg >> 3;
  const int g = rt;
  const int r0 = rt * 32;
  const int w = tid >> 6, lane = tid & 63;
  const int kw = w * 16 + (lane >> 5) * 8;            // this wave's K-offset within 128-block
  const int aoff = (r0 + (lane & 31)) * 512;          // A-frag row offset (elements)
  const int vcl = lane & 31;
  const int jc = pt * 16 + (vcl & 15) + (vcl >> 4) * 512;  // virtual col -> weight col j
  const int b512 = jc * 512, b1024 = jc * 1024;

  const int erow = tid >> 4, ecp = tid & 15;          // epilogue coords (512 elems)
  const int eo = (r0 + erow) * 512 + pt * 16 + ecp;   // global state element

  // init local h tile from global slot 0 (written by prep)
  lst[0][erow][ecp] = bf2f(stg[eo]) + bf2f(stg[PLANE + eo]);
  __syncthreads();

  unsigned gen = 1;
  float sumreg = 0.f;

  for (int t = 0; t < 400; ++t) {
    const float* xrow = x + (size_t)t * 131072 + (size_t)(r0 + (lane & 31)) * 512;

    // ---- stage A: s0 = h + sig(c)*(tanh(h0c) - h), A = [x | h], W0 (K=1024)
    {
      f32x16 acc[1] = {};
      const ushort_t* bh[1] = {w0h};
      const ushort_t* bl[1] = {w0l};
      mm_sharedA<1, 8, true>(xrow, stg + 0 * SLOT_ELEMS, bh, bl, aoff, b1024, kw, acc);
      __syncthreads();
      store_partials<1>(pp, acc, w, lane);
      __syncthreads();
      float c, h; red2<1>(pp, 0, erow, ecp, c, h);
      float sp = lst[0][erow][ecp];
      float s = sp + sigf(c) * (tanhf(h) - sp);
      lst[1][erow][ecp] = s;
      st_state(stg + 1 * SLOT_ELEMS, eo, s);
    }
    gbar_begin(flags, g, pt, gen);
    warm_w<512>(wsh + 0 * 524288, wsl + 0 * 524288, pt);   // stage B weights
    gbar_end(flags, g, gen); ++gen;

    // ---- stage B: s1 = s0 + sig(c)*(tanh(h) - s0), Ws[0]
    {
      f32x16 acc[1] = {};
      const ushort_t* bh[1] = {wsh + 0 * 524288};
      const ushort_t* bl[1] = {wsl + 0 * 524288};
      mm_sharedA<1, 4, false>(nullptr, stg + 1 * SLOT_ELEMS, bh, bl, aoff, b512, kw, acc);
      __syncthreads();
      store_partials<1>(pp, acc, w, lane);
      __syncthreads();
      float c, h; red2<1>(pp, 0, erow, ecp, c, h);
      float sp = lst[1][erow][ecp];
      float s = sp + sigf(c) * (tanhf(h) - sp);
      lst[2][erow][ecp] = s;
      sumreg += s;
      st_state(stg + 2 * SLOT_ELEMS, eo, s);
    }
    gbar_begin(flags, g, pt, gen);
    warm_w<512>(wsh + 1 * 524288, wsl + 1 * 524288, pt);   // stage C first matrix
    gbar_end(flags, g, gen); ++gen;

    // ---- stage C: s2(relu,Ws[1]) s3(relu,Ws[2]) s4(ident,Ws[3]), all from s1
    {
      f32x16 acc[3] = {};
      const ushort_t* bh[3] = {wsh + 1 * 524288, wsh + 2 * 524288, wsh + 3 * 524288};
      const ushort_t* bl[3] = {wsl + 1 * 524288, wsl + 2 * 524288, wsl + 3 * 524288};
      mm_sharedA<3, 4, false>(nullptr, stg + 2 * SLOT_ELEMS, bh, bl, aoff, b512, kw, acc);
      __syncthreads();
      store_partials<3>(pp, acc, w, lane);
      __syncthreads();
      float sp = lst[2][erow][ecp];
      float c, h;
      red2<3>(pp, 0, erow, ecp, c, h);                 // s2: relu
      float s2v = sp + sigf(c) * (fmaxf(h, 0.f) - sp);
      lst[3][erow][ecp] = s2v; sumreg += s2v;
      st_state(stg + 3 * SLOT_ELEMS, eo, s2v);
      red2<3>(pp, 1, erow, ecp, c, h);                 // s3: relu
      float s3v = sp + sigf(c) * (fmaxf(h, 0.f) - sp);
      lst[4][erow][ecp] = s3v; sumreg += s3v;
      st_state(stg + 4 * SLOT_ELEMS, eo, s3v);
      red2<3>(pp, 2, erow, ecp, c, h);                 // s4: identity, sum only
      sumreg += sp + sigf(c) * (h - sp);
    }
    gbar_begin(flags, g, pt, gen);
    warm_w<512>(wsh + 4 * 524288, wsl + 4 * 524288, pt);   // stage D first matrix
    gbar_end(flags, g, gen); ++gen;

    // ---- stage D: s5 = f(s2,tanh,Ws[4]); s7 = f(s3,tanh,Ws[6])
    {
      f32x16 acc[2] = {};
      const ushort_t* as[2] = {stg + 3 * SLOT_ELEMS, stg + 4 * SLOT_ELEMS};
      const ushort_t* bh[2] = {wsh + 4 * 524288, wsh + 6 * 524288};
      const ushort_t* bl[2] = {wsl + 4 * 524288, wsl + 6 * 524288};
      mm_pairA<2, 4>(as, bh, bl, aoff, b512, kw, acc);
      __syncthreads();
      store_partials<2>(pp, acc, w, lane);
      __syncthreads();
      float c, h;
      red2<2>(pp, 0, erow, ecp, c, h);                 // s5
      float sp = lst[3][erow][ecp];
      float s5v = sp + sigf(c) * (tanhf(h) - sp);
      lst[5][erow][ecp] = s5v; sumreg += s5v;
      st_state(stg + 5 * SLOT_ELEMS, eo, s5v);
      red2<2>(pp, 1, erow, ecp, c, h);                 // s7: sum only
      float sp3 = lst[4][erow][ecp];
      sumreg += sp3 + sigf(c) * (tanhf(h) - sp3);
    }
    gbar_begin(flags, g, pt, gen);
    warm_w<512>(wsh + 5 * 524288, wsl + 5 * 524288, pt);   // stage E first matrix
    if (t + 1 < 400) warm_x(x + (size_t)(t + 1) * 131072 + (size_t)r0 * 512);
    gbar_end(flags, g, gen); ++gen;

    // ---- stage E: s6 = f(s5,sigmoid,Ws[5]); s8 = f(s5,relu,Ws[7]); mean; h
    {
      f32x16 acc[2] = {};
      const ushort_t* bh[2] = {wsh + 5 * 524288, wsh + 7 * 524288};
      const ushort_t* bl[2] = {wsl + 5 * 524288, wsl + 7 * 524288};
      mm_sharedA<2, 4, false>(nullptr, stg + 5 * SLOT_ELEMS, bh, bl, aoff, b512, kw, acc);
      __syncthreads();
      store_partials<2>(pp, acc, w, lane);
      __syncthreads();
      float c, h;
      float sp = lst[5][erow][ecp];
      red2<2>(pp, 0, erow, ecp, c, h);                 // s6: sigmoid
      sumreg += sp + sigf(c) * (sigf(h) - sp);
      red2<2>(pp, 1, erow, ecp, c, h);                 // s8: relu
      sumreg += sp + sigf(c) * (fmaxf(h, 0.f) - sp);
      float hn = sumreg * 0.125f;
      out[(size_t)t * 131072 + eo] = hn;
      if (t == 399) out[(size_t)400 * 131072 + eo] = hn;
      lst[0][erow][ecp] = hn;
      st_state(stg + 0 * SLOT_ELEMS, eo, hn);
      sumreg = 0.f;
    }
    gbar_begin(flags, g, pt, gen);
    warm_w<1024>(w0h, w0l, pt);                            // next step's W0
    gbar_end(flags, g, gen); ++gen;
  }
}

// ---------------- host launch ----------------------------------------------
extern "C" void kernel_launch(void* const* d_in, const int* in_sizes, int n_in,
                              void* d_out, int out_size, void* d_ws, size_t ws_size,
                              hipStream_t stream) {
  const float* x  = (const float*)d_in[0];
  const float* h0 = (const float*)d_in[1];
  const float* W0 = (const float*)d_in[2];
  const float* Ws = (const float*)d_in[3];
  float* out = (float*)d_out;
  char* ws = (char*)d_ws;

  (void)in_sizes; (void)n_in; (void)out_size; (void)ws_size;

  (void)hipMemsetAsync(ws + WS_BAR, 0, 16384, stream);
  hipLaunchKernelGGL(prep_kernel, dim3(2048), dim3(256), 0, stream, W0, Ws, h0, ws);

  void* args[3] = {(void*)&x, (void*)&out, (void*)&ws};
  (void)hipLaunchCooperativeKernel((void*)rnn_main, dim3(256), dim3(512), args, 0, stream);
}